// Round 2
// baseline (31790.958 us; speedup 1.0000x reference)
//
#include <hip/hip_runtime.h>

#define D_ 512
#define H_ 1024
#define L_ 4096
#define CS_ 64
#define NCH_ 64
#define RACT_ 256
#define LR_ 0.1f
#define MOM_ 0.95f
#define NSA_ 3.4445f
#define NSB_ (-4.7750f)
#define NSC_ 2.0315f

using bf16x8 = __attribute__((ext_vector_type(8))) short;
using f32x4  = __attribute__((ext_vector_type(4))) float;

__device__ __forceinline__ short f2bs(float f) {
  unsigned u = __builtin_bit_cast(unsigned, f);
  unsigned r = (u + 0x7fffu + ((u >> 16) & 1u)) >> 16;  // RNE
  return (short)r;
}
__device__ __forceinline__ float bs2f(short s) {
  unsigned u = ((unsigned)(unsigned short)s) << 16;
  return __builtin_bit_cast(float, u);
}
// split fp32 -> hi + lo bf16 (error ~2^-18 relative)
__device__ __forceinline__ void split2(float v, short& h, short& l) {
  h = f2bs(v);
  l = f2bs(v - bs2f(h));
}

#define MFMA16(a, b, c) __builtin_amdgcn_mfma_f32_16x16x32_bf16(a, b, c, 0, 0, 0)

__device__ __forceinline__ void zero_acc(f32x4 (&acc)[2][2]) {
  f32x4 z = {0.f, 0.f, 0.f, 0.f};
  acc[0][0] = z; acc[0][1] = z; acc[1][0] = z; acc[1][1] = z;
}

// Split-bf16 NT GEMM: C[m][n] = sum_k A[m][k]*Bt[n][k], A=Ah+Al, B=Bh+Bl.
// 3 MFMA passes (hh, hl, lh); lo*lo dropped (~2^-18 rel). 4 waves/block,
// 64x64 C tile, wave computes 32x32 via 2x2 16x16x32 fragments.
__device__ __forceinline__ void mma_nt_split(
    const short* __restrict__ Ah, const short* __restrict__ Al, int lda,
    const short* __restrict__ Bh, const short* __restrict__ Bl, int ldb,
    int K, int m0, int n0, f32x4 (&acc)[2][2]) {
  const int lane = threadIdx.x & 63;
  const int lm = lane & 15, kq = lane >> 4;
  const size_t aoff = (size_t)(m0 + lm) * lda + kq * 8;
  const size_t boff = (size_t)(n0 + lm) * ldb + kq * 8;
  const size_t a1 = aoff + (size_t)16 * lda;
  const size_t b1 = boff + (size_t)16 * ldb;
#pragma unroll 2
  for (int k = 0; k < K; k += 32) {
    bf16x8 ah0 = *(const bf16x8*)(Ah + aoff + k);
    bf16x8 ah1 = *(const bf16x8*)(Ah + a1 + k);
    bf16x8 bh0 = *(const bf16x8*)(Bh + boff + k);
    bf16x8 bh1 = *(const bf16x8*)(Bh + b1 + k);
    bf16x8 al0 = *(const bf16x8*)(Al + aoff + k);
    bf16x8 al1 = *(const bf16x8*)(Al + a1 + k);
    bf16x8 bl0 = *(const bf16x8*)(Bl + boff + k);
    bf16x8 bl1 = *(const bf16x8*)(Bl + b1 + k);
    acc[0][0] = MFMA16(ah0, bh0, acc[0][0]);
    acc[0][1] = MFMA16(ah0, bh1, acc[0][1]);
    acc[1][0] = MFMA16(ah1, bh0, acc[1][0]);
    acc[1][1] = MFMA16(ah1, bh1, acc[1][1]);
    acc[0][0] = MFMA16(ah0, bl0, acc[0][0]);
    acc[0][1] = MFMA16(ah0, bl1, acc[0][1]);
    acc[1][0] = MFMA16(ah1, bl0, acc[1][0]);
    acc[1][1] = MFMA16(ah1, bl1, acc[1][1]);
    acc[0][0] = MFMA16(al0, bh0, acc[0][0]);
    acc[0][1] = MFMA16(al0, bh1, acc[0][1]);
    acc[1][0] = MFMA16(al1, bh0, acc[1][0]);
    acc[1][1] = MFMA16(al1, bh1, acc[1][1]);
  }
}

#define TILE_SETUP(MT_SHIFT, NT_MASK)                         \
  const int bid = blockIdx.x;                                 \
  const int mt = (bid & 127) >> MT_SHIFT;                     \
  const int nt = bid & NT_MASK;                               \
  const int wave = threadIdx.x >> 6;                          \
  const int lane = threadIdx.x & 63;                          \
  const int lm = lane & 15, kq = lane >> 4;                   \
  const int m0 = mt * 64 + (wave >> 1) * 32;                  \
  const int n0 = nt * 64 + (wave & 1) * 32;

#define EPI_FOR                                               \
  _Pragma("unroll") for (int i = 0; i < 2; i++)               \
  _Pragma("unroll") for (int j = 0; j < 2; j++)               \
  _Pragma("unroll") for (int e = 0; e < 4; e++)

#define EPI_IDX int gm = m0 + i * 16 + kq * 4 + e, gn = n0 + j * 16 + lm;

// ---------------- init: fp32 weights, split mirrors, zero momentum ----------
__global__ __launch_bounds__(256) void muon_init(
    const float* __restrict__ w1in, const float* __restrict__ w2in,
    float* __restrict__ w1f, float* __restrict__ w2f,
    float* __restrict__ buf1, float* __restrict__ buf2t,
    short* __restrict__ w1bth, short* __restrict__ w1btl,
    short* __restrict__ w2bh, short* __restrict__ w2bl,
    short* __restrict__ w2bth, short* __restrict__ w2btl) {
  int idx = blockIdx.x * 256 + threadIdx.x;  // D_*H_ threads
  float a = w1in[idx], b = w2in[idx];
  w1f[idx] = a; w2f[idx] = b;
  buf1[idx] = 0.f; buf2t[idx] = 0.f;
  short h, l;
  int d1 = idx >> 10, h1 = idx & 1023;        // w1 is [d][h]
  split2(a, h, l);
  w1bth[(size_t)h1 * D_ + d1] = h; w1btl[(size_t)h1 * D_ + d1] = l;
  int h2 = idx >> 9, d2 = idx & 511;          // w2 is [h][d]
  split2(b, h, l);
  w2bh[idx] = h; w2bl[idx] = l;
  w2bth[(size_t)d2 * H_ + h2] = h; w2btl[(size_t)d2 * H_ + h2] = l;
}

// ---------------- kx: split active x chunk (256 rows) + transpose -----------
__global__ __launch_bounds__(256) void muon_kx(
    const float* __restrict__ kin, int c,
    short* __restrict__ xah, short* __restrict__ xal,
    short* __restrict__ xaTh, short* __restrict__ xaTl) {
  int base = blockIdx.x * 1024 + threadIdx.x;  // 128 blocks * 4 elems
#pragma unroll
  for (int r4 = 0; r4 < 4; r4++) {
    int idx = base + r4 * 256;
    int r = idx >> 9, d = idx & 511;
    int b = r >> 4, t = r & 15;
    float v = kin[(size_t)(b * L_ + c * CS_ + t) * D_ + d];
    short h, l; split2(v, h, l);
    xah[idx] = h; xal[idx] = l;
    xaTh[(size_t)d * RACT_ + r] = h; xaTl[(size_t)d * RACT_ + r] = l;
  }
}

// ---------------- k1a: l1 = tanh(x @ w1); write l1/l1T planes + deriv -------
__global__ __launch_bounds__(256) void muon_k1a(
    const short* __restrict__ xah, const short* __restrict__ xal,
    const short* __restrict__ w1bth, const short* __restrict__ w1btl,
    short* __restrict__ l1h, short* __restrict__ l1l,
    short* __restrict__ l1Th, short* __restrict__ l1Tl,
    float* __restrict__ deriv) {
  const int bid = blockIdx.x;            // grid 64: mt 0..3, nt 0..15
  const int mt = bid >> 4, nt = bid & 15;
  const int wave = threadIdx.x >> 6, lane = threadIdx.x & 63;
  const int lm = lane & 15, kq = lane >> 4;
  const int m0 = mt * 64 + (wave >> 1) * 32;
  const int n0 = nt * 64 + (wave & 1) * 32;
  f32x4 acc[2][2]; zero_acc(acc);
  mma_nt_split(xah, xal, D_, w1bth, w1btl, D_, D_, m0, n0, acc);
  EPI_FOR {
    EPI_IDX
    float l1v = tanhf(acc[i][j][e]);
    short h, l; split2(l1v, h, l);
    l1h[(size_t)gm * H_ + gn] = h; l1l[(size_t)gm * H_ + gn] = l;
    l1Th[(size_t)gn * RACT_ + gm] = h; l1Tl[(size_t)gn * RACT_ + gm] = l;
    deriv[(size_t)gm * H_ + gn] = 1.f - l1v * l1v;
  }
}

// ---------------- k1b: out = l1 @ w2; dOut = mask * 2/1024 * (out - vt) -----
__global__ __launch_bounds__(256) void muon_k1b(
    const float* __restrict__ vin,
    const short* __restrict__ l1h, const short* __restrict__ l1l,
    const short* __restrict__ w2bth, const short* __restrict__ w2btl,
    short* __restrict__ dOh, short* __restrict__ dOl,
    short* __restrict__ dOTh, short* __restrict__ dOTl, int c) {
  const int bid = blockIdx.x;            // grid 32: mt 0..3, nt 0..7
  const int mt = bid >> 3, nt = bid & 7;
  const int wave = threadIdx.x >> 6, lane = threadIdx.x & 63;
  const int lm = lane & 15, kq = lane >> 4;
  const int m0 = mt * 64 + (wave >> 1) * 32;
  const int n0 = nt * 64 + (wave & 1) * 32;
  f32x4 acc[2][2]; zero_acc(acc);
  mma_nt_split(l1h, l1l, H_, w2bth, w2btl, H_, H_, m0, n0, acc);
  EPI_FOR {
    EPI_IDX
    int b = gm >> 4, t = gm & 15;
    bool mk = (t <= b) && (b - t <= 7);
    float dv = 0.f;
    if (mk) {
      float vt = vin[(size_t)(b * L_ + c * CS_ + t) * D_ + gn];
      dv = (2.0f / 1024.0f) * (acc[i][j][e] - vt);
    }
    short h, l; split2(dv, h, l);
    dOh[(size_t)gm * D_ + gn] = h; dOl[(size_t)gm * D_ + gn] = l;
    dOTh[(size_t)gn * RACT_ + gm] = h; dOTl[(size_t)gn * RACT_ + gm] = l;
  }
}

// ---------------- k1c: dpre = (dOut @ w2^T) * deriv; write dpreT ------------
__global__ __launch_bounds__(256) void muon_k1c(
    const short* __restrict__ dOh, const short* __restrict__ dOl,
    const short* __restrict__ w2bh, const short* __restrict__ w2bl,
    const float* __restrict__ deriv,
    short* __restrict__ dpTh, short* __restrict__ dpTl) {
  const int bid = blockIdx.x;            // grid 64: mt 0..3, nt 0..15
  const int mt = bid >> 4, nt = bid & 15;
  const int wave = threadIdx.x >> 6, lane = threadIdx.x & 63;
  const int lm = lane & 15, kq = lane >> 4;
  const int m0 = mt * 64 + (wave >> 1) * 32;
  const int n0 = nt * 64 + (wave & 1) * 32;
  f32x4 acc[2][2]; zero_acc(acc);
  mma_nt_split(dOh, dOl, D_, w2bh, w2bl, D_, D_, m0, n0, acc);
  EPI_FOR {
    EPI_IDX
    float dp = acc[i][j][e] * deriv[(size_t)gm * H_ + gn];
    short h, l; split2(dp, h, l);
    dpTh[(size_t)gn * RACT_ + gm] = h; dpTl[(size_t)gn * RACT_ + gm] = l;
  }
}

// ---------------- k2: g1 = x^T dpre, g2t = dOut^T l1; momentum + nesterov ---
__global__ __launch_bounds__(256) void muon_k2(
    const short* __restrict__ xaTh, const short* __restrict__ xaTl,
    const short* __restrict__ dpTh, const short* __restrict__ dpTl,
    const short* __restrict__ dOTh, const short* __restrict__ dOTl,
    const short* __restrict__ l1Th, const short* __restrict__ l1Tl,
    float* __restrict__ buf1, float* __restrict__ buf2t,
    float* __restrict__ Gn1, float* __restrict__ Gn2,
    float* __restrict__ partial) {
  const int job = blockIdx.x >> 7;       // grid 256
  TILE_SETUP(4, 15)
  const short* Ah = job ? dOTh : xaTh;
  const short* Al = job ? dOTl : xaTl;
  const short* Bh = job ? l1Th : dpTh;
  const short* Bl = job ? l1Tl : dpTl;
  float* buf = job ? buf2t : buf1;
  float* Gn  = job ? Gn2 : Gn1;
  f32x4 acc[2][2]; zero_acc(acc);
  mma_nt_split(Ah, Al, RACT_, Bh, Bl, RACT_, RACT_, m0, n0, acc);
  float part = 0.f;
  EPI_FOR {
    EPI_IDX
    size_t idx = (size_t)gm * H_ + gn;
    float g = acc[i][j][e];
    float bn = MOM_ * buf[idx] + g;
    buf[idx] = bn;
    float gv = g + MOM_ * bn;  // nesterov
    Gn[idx] = gv;
    part += gv * gv;
  }
  for (int off = 32; off > 0; off >>= 1) part += __shfl_down(part, off, 64);
  __shared__ float red[4];
  if (lane == 0) red[wave] = part;
  __syncthreads();
  if (threadIdx.x == 0) partial[bid] = red[0] + red[1] + red[2] + red[3];
}

// ---------------- k3: X0 = Gn / (||Gn|| + 1e-7), split + transposed ---------
__global__ __launch_bounds__(256) void muon_k3(
    const float* __restrict__ Gn1, const float* __restrict__ Gn2,
    const float* __restrict__ partial,
    short* __restrict__ Xph, short* __restrict__ Xpl,
    short* __restrict__ Xth, short* __restrict__ Xtl) {
  const int job = blockIdx.x >> 8;       // grid 512, 2048 elems/block
  const int blk = blockIdx.x & 255;
  const int t = threadIdx.x;
  // deterministic norm: fixed-order reduce of 128 per-block partials
  float v = (t < 128) ? partial[job * 128 + t] : 0.f;
  for (int off = 32; off > 0; off >>= 1) v += __shfl_down(v, off, 64);
  __shared__ float wred[2];
  if ((t & 63) == 0 && t < 128) wred[t >> 6] = v;
  __syncthreads();
  float s = 1.f / (sqrtf(wred[0] + wred[1]) + 1e-7f);
  const float* G = job ? Gn2 : Gn1;
  short* xph = Xph + (size_t)job * (D_ * H_);
  short* xpl = Xpl + (size_t)job * (D_ * H_);
  short* xth = Xth + (size_t)job * (D_ * H_);
  short* xtl = Xtl + (size_t)job * (D_ * H_);
  int base = blk * 2048 + t;
#pragma unroll
  for (int r = 0; r < 8; r++) {
    int idx = base + r * 256;
    int m = idx >> 10, n = idx & 1023;
    short h, l; split2(G[idx] * s, h, l);
    xph[idx] = h; xpl[idx] = l;
    xth[(size_t)n * D_ + m] = h; xtl[(size_t)n * D_ + m] = l;
  }
}

// ---------------- k4: A = X @ X^T -------------------------------------------
__global__ __launch_bounds__(256) void muon_k4(
    const short* __restrict__ Xph, const short* __restrict__ Xpl,
    short* __restrict__ Ah, short* __restrict__ Al) {
  const int job = blockIdx.x >> 6;       // grid 128: mt 0..7, nt 0..7
  const int bid = blockIdx.x;
  const int mt = (bid & 63) >> 3, nt = bid & 7;
  const int wave = threadIdx.x >> 6, lane = threadIdx.x & 63;
  const int lm = lane & 15, kq = lane >> 4;
  const int m0 = mt * 64 + (wave >> 1) * 32;
  const int n0 = nt * 64 + (wave & 1) * 32;
  const short* xh = Xph + (size_t)job * (D_ * H_);
  const short* xl = Xpl + (size_t)job * (D_ * H_);
  f32x4 acc[2][2]; zero_acc(acc);
  mma_nt_split(xh, xl, H_, xh, xl, H_, H_, m0, n0, acc);
  short* ah = Ah + (size_t)job * (D_ * D_);
  short* al = Al + (size_t)job * (D_ * D_);
  EPI_FOR {
    EPI_IDX
    short h, l; split2(acc[i][j][e], h, l);
    ah[(size_t)gm * D_ + gn] = h; al[(size_t)gm * D_ + gn] = l;
  }
}

// ---------------- k5: Bm = b*A + c*(A@A) ------------------------------------
__global__ __launch_bounds__(256) void muon_k5(
    const short* __restrict__ Ah, const short* __restrict__ Al,
    short* __restrict__ Bmh, short* __restrict__ Bml) {
  const int job = blockIdx.x >> 6;
  const int bid = blockIdx.x;
  const int mt = (bid & 63) >> 3, nt = bid & 7;
  const int wave = threadIdx.x >> 6, lane = threadIdx.x & 63;
  const int lm = lane & 15, kq = lane >> 4;
  const int m0 = mt * 64 + (wave >> 1) * 32;
  const int n0 = nt * 64 + (wave & 1) * 32;
  const short* ah = Ah + (size_t)job * (D_ * D_);
  const short* al = Al + (size_t)job * (D_ * D_);
  f32x4 acc[2][2]; zero_acc(acc);
  mma_nt_split(ah, al, D_, ah, al, D_, D_, m0, n0, acc);  // A symmetric
  short* bh = Bmh + (size_t)job * (D_ * D_);
  short* bl = Bml + (size_t)job * (D_ * D_);
  EPI_FOR {
    EPI_IDX
    size_t ii = (size_t)gm * D_ + gn;
    float av = bs2f(ah[ii]) + bs2f(al[ii]);
    short h, l; split2(NSB_ * av + NSC_ * acc[i][j][e], h, l);
    bh[ii] = h; bl[ii] = l;
  }
}

// ---------------- k6: Xn = a*X + Bm @ X  (last iter: weight update) ---------
__global__ __launch_bounds__(256) void muon_k6(
    const short* __restrict__ Bmh, const short* __restrict__ Bml,
    const short* __restrict__ Xth, const short* __restrict__ Xtl,
    const short* __restrict__ Xph, const short* __restrict__ Xpl,
    short* __restrict__ XphN, short* __restrict__ XplN,
    short* __restrict__ XthN, short* __restrict__ XtlN,
    float* __restrict__ w1f, float* __restrict__ w2f,
    short* __restrict__ w1bth, short* __restrict__ w1btl,
    short* __restrict__ w2bh, short* __restrict__ w2bl,
    short* __restrict__ w2bth, short* __restrict__ w2btl, int last) {
  const size_t MSZ = (size_t)D_ * H_;
  const int job = blockIdx.x >> 7;       // grid 256
  TILE_SETUP(4, 15)
  (void)bid;
  const short* bmh = Bmh + (size_t)job * (D_ * D_);
  const short* bml = Bml + (size_t)job * (D_ * D_);
  f32x4 acc[2][2]; zero_acc(acc);
  mma_nt_split(bmh, bml, D_, Xth + job * MSZ, Xtl + job * MSZ, D_, D_, m0, n0, acc);
  EPI_FOR {
    EPI_IDX
    size_t idx = (size_t)gm * H_ + gn;
    float xv = NSA_ * (bs2f(Xph[job * MSZ + idx]) + bs2f(Xpl[job * MSZ + idx]))
             + acc[i][j][e];
    short h, l;
    if (!last) {
      split2(xv, h, l);
      XphN[job * MSZ + idx] = h; XplN[job * MSZ + idx] = l;
      XthN[job * MSZ + (size_t)gn * D_ + gm] = h;
      XtlN[job * MSZ + (size_t)gn * D_ + gm] = l;
    } else if (job == 0) {
      float nv = w1f[idx] - LR_ * xv;     // w1 [d][h] == X1 orientation
      w1f[idx] = nv;
      split2(nv, h, l);
      w1bth[(size_t)gn * D_ + gm] = h; w1btl[(size_t)gn * D_ + gm] = l;
    } else {
      size_t i2 = (size_t)gn * D_ + gm;   // w2 [h][d], u2 = X2^T
      float nv = w2f[i2] - LR_ * xv;
      w2f[i2] = nv;
      split2(nv, h, l);
      w2bh[i2] = h; w2bl[i2] = l;
      w2bth[idx] = h; w2btl[idx] = l;
    }
  }
}

// ---------------- kxf: split full last chunk (1024 rows) --------------------
__global__ __launch_bounds__(256) void muon_kxf(
    const float* __restrict__ kin, short* __restrict__ xfh, short* __restrict__ xfl) {
  int base = blockIdx.x * 1024 + threadIdx.x;  // 512 blocks * 4 elems
#pragma unroll
  for (int r4 = 0; r4 < 4; r4++) {
    int idx = base + r4 * 256;
    int r = idx >> 9, d = idx & 511;
    int b = r >> 6, t = r & 63;
    float v = kin[(size_t)(b * L_ + (NCH_ - 1) * CS_ + t) * D_ + d];
    short h, l; split2(v, h, l);
    xfh[idx] = h; xfl[idx] = l;
  }
}

// ---------------- k8a: final forward layer 1 --------------------------------
__global__ __launch_bounds__(256) void muon_k8a(
    const short* __restrict__ xfh, const short* __restrict__ xfl,
    const short* __restrict__ w1bth, const short* __restrict__ w1btl,
    short* __restrict__ l1fh, short* __restrict__ l1fl) {
  const int bid = blockIdx.x;            // grid 256: mt 0..15, nt 0..15
  const int mt = bid >> 4, nt = bid & 15;
  const int wave = threadIdx.x >> 6, lane = threadIdx.x & 63;
  const int lm = lane & 15, kq = lane >> 4;
  const int m0 = mt * 64 + (wave >> 1) * 32;
  const int n0 = nt * 64 + (wave & 1) * 32;
  f32x4 acc[2][2]; zero_acc(acc);
  mma_nt_split(xfh, xfl, D_, w1bth, w1btl, D_, D_, m0, n0, acc);
  EPI_FOR {
    EPI_IDX
    short h, l; split2(tanhf(acc[i][j][e]), h, l);
    l1fh[(size_t)gm * H_ + gn] = h; l1fl[(size_t)gm * H_ + gn] = l;
  }
}

// ---------------- k8b: final forward layer 2 → d_out ------------------------
__global__ __launch_bounds__(256) void muon_k8b(
    const short* __restrict__ l1fh, const short* __restrict__ l1fl,
    const short* __restrict__ w2bth, const short* __restrict__ w2btl,
    float* __restrict__ out) {
  const int bid = blockIdx.x;            // grid 128: mt 0..15, nt 0..7
  const int mt = bid >> 3, nt = bid & 7;
  const int wave = threadIdx.x >> 6, lane = threadIdx.x & 63;
  const int lm = lane & 15, kq = lane >> 4;
  const int m0 = mt * 64 + (wave >> 1) * 32;
  const int n0 = nt * 64 + (wave & 1) * 32;
  f32x4 acc[2][2]; zero_acc(acc);
  mma_nt_split(l1fh, l1fl, H_, w2bth, w2btl, H_, H_, m0, n0, acc);
  EPI_FOR {
    EPI_IDX
    out[(size_t)gm * D_ + gn] = acc[i][j][e];
  }
}

extern "C" void kernel_launch(void* const* d_in, const int* in_sizes, int n_in,
                              void* d_out, int out_size, void* d_ws, size_t ws_size,
                              hipStream_t stream) {
  const float* kin  = (const float*)d_in[0];
  const float* vin  = (const float*)d_in[1];
  const float* w1in = (const float*)d_in[2];
  const float* w2in = (const float*)d_in[3];
  float* out = (float*)d_out;

  char* p = (char*)d_ws;
  auto take = [&](size_t bytes) { char* r = p; p += (bytes + 255) & ~(size_t)255; return r; };
  const size_t MSZ = (size_t)D_ * H_;    // 524288
  const size_t ASZ = (size_t)D_ * D_;    // 262144
  const size_t L1SZ = (size_t)RACT_ * H_;  // 262144
  const size_t DOSZ = (size_t)RACT_ * D_;  // 131072

  float* w1f   = (float*)take(MSZ * 4);
  float* w2f   = (float*)take(MSZ * 4);
  float* buf1  = (float*)take(MSZ * 4);
  float* buf2t = (float*)take(MSZ * 4);
  float* Gn1   = (float*)take(MSZ * 4);
  float* Gn2   = (float*)take(MSZ * 4);
  float* deriv = (float*)take(L1SZ * 4);
  float* partial = (float*)take(256 * 4);
  short* w1bth = (short*)take(MSZ * 2);
  short* w1btl = (short*)take(MSZ * 2);
  short* w2bh  = (short*)take(MSZ * 2);
  short* w2bl  = (short*)take(MSZ * 2);
  short* w2bth = (short*)take(MSZ * 2);
  short* w2btl = (short*)take(MSZ * 2);
  short* Xph[2], *Xpl[2], *Xth[2], *Xtl[2];
  for (int i = 0; i < 2; i++) {
    Xph[i] = (short*)take(2 * MSZ * 2);
    Xpl[i] = (short*)take(2 * MSZ * 2);
    Xth[i] = (short*)take(2 * MSZ * 2);
    Xtl[i] = (short*)take(2 * MSZ * 2);
  }
  short* Ah  = (short*)take(2 * ASZ * 2);
  short* Al  = (short*)take(2 * ASZ * 2);
  short* Bmh = (short*)take(2 * ASZ * 2);
  short* Bml = (short*)take(2 * ASZ * 2);
  short* l1h = (short*)take(L1SZ * 2);
  short* l1l = (short*)take(L1SZ * 2);
  short* l1Th = (short*)take(L1SZ * 2);
  short* l1Tl = (short*)take(L1SZ * 2);
  short* dOh  = (short*)take(DOSZ * 2);
  short* dOl  = (short*)take(DOSZ * 2);
  short* dOTh = (short*)take(DOSZ * 2);
  short* dOTl = (short*)take(DOSZ * 2);
  short* dpTh = (short*)take(L1SZ * 2);
  short* dpTl = (short*)take(L1SZ * 2);
  short* xah  = (short*)take(DOSZ * 2);
  short* xal  = (short*)take(DOSZ * 2);
  short* xaTh = (short*)take(DOSZ * 2);
  short* xaTl = (short*)take(DOSZ * 2);
  // final-stage buffers alias dead NS buffers (chunk loop finished):
  short* xfh  = Xph[0];             // 1024x512
  short* xfl  = Xph[0] + MSZ;
  short* l1fh = Xpl[0];             // 1024x1024 = 2*MSZ
  short* l1fl = Xph[1];

  muon_init<<<2048, 256, 0, stream>>>(w1in, w2in, w1f, w2f, buf1, buf2t,
                                      w1bth, w1btl, w2bh, w2bl, w2bth, w2btl);
  for (int c = 0; c < NCH_ - 1; c++) {
    muon_kx<<<128, 256, 0, stream>>>(kin, c, xah, xal, xaTh, xaTl);
    muon_k1a<<<64, 256, 0, stream>>>(xah, xal, w1bth, w1btl, l1h, l1l, l1Th, l1Tl, deriv);
    muon_k1b<<<32, 256, 0, stream>>>(vin, l1h, l1l, w2bth, w2btl, dOh, dOl, dOTh, dOTl, c);
    muon_k1c<<<64, 256, 0, stream>>>(dOh, dOl, w2bh, w2bl, deriv, dpTh, dpTl);
    muon_k2<<<256, 256, 0, stream>>>(xaTh, xaTl, dpTh, dpTl, dOTh, dOTl, l1Th, l1Tl,
                                     buf1, buf2t, Gn1, Gn2, partial);
    muon_k3<<<512, 256, 0, stream>>>(Gn1, Gn2, partial, Xph[0], Xpl[0], Xth[0], Xtl[0]);
    for (int it = 0; it < 5; it++) {
      int cur = it & 1, nx = cur ^ 1;
      muon_k4<<<128, 256, 0, stream>>>(Xph[cur], Xpl[cur], Ah, Al);
      muon_k5<<<128, 256, 0, stream>>>(Ah, Al, Bmh, Bml);
      muon_k6<<<256, 256, 0, stream>>>(Bmh, Bml, Xth[cur], Xtl[cur], Xph[cur], Xpl[cur],
                                       Xph[nx], Xpl[nx], Xth[nx], Xtl[nx],
                                       w1f, w2f, w1bth, w1btl, w2bh, w2bl,
                                       w2bth, w2btl, it == 4 ? 1 : 0);
    }
  }
  muon_kxf<<<512, 256, 0, stream>>>(kin, xfh, xfl);
  muon_k8a<<<256, 256, 0, stream>>>(xfh, xfl, w1bth, w1btl, l1fh, l1fl);
  muon_k8b<<<128, 256, 0, stream>>>(l1fh, l1fl, w2bth, w2btl, out);
}